// Round 3
// baseline (641.834 us; speedup 1.0000x reference)
//
#include <hip/hip_runtime.h>

typedef unsigned short u16;
typedef __bf16 bf16x8 __attribute__((ext_vector_type(8)));
typedef float f32x4 __attribute__((ext_vector_type(4)));
typedef u16 u16x8 __attribute__((ext_vector_type(8)));

#define TM 32
#define LDP 264          // padded LDS row stride (elems)
#define BTOT 32768

// bf16 frag-swizzled weight layout inside d_ws (element offsets)
#define OFF_WIH 0
#define OFF_WHH 524288
#define OFF_WQ  786432
#define OFF_WK  851968
#define OFF_WBA 917504
#define OFF_WAT 1179648
#define OFF_WP1 1310720
#define OFF_WP2 1343488
#define OFF_WV1 1351680
#define OFF_WV2 1368064

__device__ __forceinline__ float b2f(u16 h) {
    union { unsigned int u; float f; } v; v.u = ((unsigned int)h) << 16; return v.f;
}
__device__ __forceinline__ u16 f2b(float f) {
    union { float f; unsigned int u; } v; v.f = f;
    unsigned int u = v.u + 0x7fffu + ((v.u >> 16) & 1u);
    return (u16)(u >> 16);
}
__device__ __forceinline__ float sigm(float x) { return 1.0f / (1.0f + __expf(-x)); }
__device__ __forceinline__ float tanhfast(float x) { return 1.0f - 2.0f / (__expf(2.0f * x) + 1.0f); }
__device__ __forceinline__ float relu(float x) { return x > 0.0f ? x : 0.0f; }
__device__ __forceinline__ bf16x8 ld8(const u16* p) { return *(const bf16x8*)p; }
__device__ __forceinline__ f32x4 mfma16(bf16x8 a, bf16x8 b, f32x4 c) {
    return __builtin_amdgcn_mfma_f32_16x16x32_bf16(a, b, c, 0, 0, 0);
}

// dtype probe (data is f32): bf16-packed words carry an exponent field in
// bits 7..14; f32 words have mantissa bits there.
__device__ __forceinline__ bool detect_f32(const void* imgp) {
    const unsigned int* w = (const unsigned int*)imgp;
    int hits = 0;
    #pragma unroll
    for (int i = 0; i < 16; ++i) {
        int e0 = (w[i] >> 7) & 0xFF;
        hits += (e0 >= 100 && e0 <= 140) ? 1 : 0;
    }
    return hits < 10;
}

__device__ __forceinline__ float ldin(const void* p, size_t i, bool f32) {
    return f32 ? ((const float*)p)[i] : b2f(((const u16*)p)[i]);
}
__device__ __forceinline__ void stout(void* o, size_t i, float v, bool f32) {
    if (f32) ((float*)o)[i] = v; else ((u16*)o)[i] = f2b(v);
}
// non-temporal variants for streaming (read-once / write-once) traffic.
__device__ __forceinline__ void stout_nt(void* o, size_t i, float v, bool f32) {
    if (f32) __builtin_nontemporal_store(v, (float*)o + i);
    else ((u16*)o)[i] = f2b(v);
}
__device__ __forceinline__ bf16x8 ldg8f_nt(const void* p, size_t i, bool f32) {
    u16 t[8];
    if (f32) {
        const f32x4* q = (const f32x4*)((const float*)p + i);
        f32x4 a = __builtin_nontemporal_load(q);
        f32x4 b = __builtin_nontemporal_load(q + 1);
        #pragma unroll
        for (int j = 0; j < 4; ++j) { t[j] = f2b(a[j]); t[4 + j] = f2b(b[j]); }
    } else {
        *(u16x8*)t = *(const u16x8*)((const u16*)p + i);
    }
    return *(bf16x8*)t;
}

// ---- weight pre-conversion + MFMA-frag swizzle ----
// dst chunk g (8 elems): lane = g&63, fi = g>>6, kk = fi%KK, tn = fi/KK
// src: row = tn*16 + (lane&15), col = kk*32 + (lane>>4)*8  of W[N,K] row-major
struct CvtArgs {
    const void* src[10];
    unsigned int nchunk[10];
    unsigned int off8[10];
    unsigned int Kdim[10];
    const void* det;
};

__global__ __launch_bounds__(256) void cvt_weights(CvtArgs a, u16* ws) {
    const bool f32 = detect_f32(a.det);
    const int p = blockIdx.x;
    const void* s = a.src[p];
    const unsigned int K = a.Kdim[p];
    const unsigned int KK = K >> 5;          // pow2 for all matrices
    const unsigned int msk = KK - 1u;
    const unsigned int sh = 31 - __clz((int)KK);
    const unsigned int n = a.nchunk[p];
    for (unsigned int g = blockIdx.y * blockDim.x + threadIdx.x; g < n;
         g += gridDim.y * blockDim.x) {
        const unsigned int lane = g & 63u;
        const unsigned int fi = g >> 6;
        const unsigned int kk = fi & msk;
        const unsigned int tn = fi >> sh;
        const unsigned int row = tn * 16u + (lane & 15u);
        const unsigned int col = kk * 32u + ((lane >> 4) << 3);
        const size_t si = (size_t)row * K + col;
        u16 t[8];
        if (f32) {
            const float* q = (const float*)s + si;
            #pragma unroll
            for (int j = 0; j < 8; ++j) t[j] = f2b(__builtin_nontemporal_load(q + j));
        } else {
            *(u16x8*)t = *(const u16x8*)((const u16*)s + si);
        }
        ((u16x8*)ws)[a.off8[p] + g] = *(u16x8*)t;
    }
}

// TM=32: LDS ~70 KB -> 2 blocks/CU resident (4 waves/SIMD).
__global__ __launch_bounds__(512, 4) void ac_fused(
    const void* __restrict__ img, const int* __restrict__ insn,
    const void* __restrict__ hx_in, const void* __restrict__ cx_in,
    const void* __restrict__ query,
    const void* __restrict__ emb, const void* __restrict__ w_ta, const void* __restrict__ b_ta,
    const void* __restrict__ b_ih, const void* __restrict__ b_hh,
    const void* __restrict__ b_q, const void* __restrict__ b_k,
    const void* __restrict__ b_ba, const void* __restrict__ b_at,
    const void* __restrict__ b_p1, const void* __restrict__ b_p2,
    const void* __restrict__ w_p3, const void* __restrict__ b_p3,
    const void* __restrict__ b_v1, const void* __restrict__ b_v2,
    const void* __restrict__ w_v3, const void* __restrict__ b_v3,
    const u16* __restrict__ wsb, void* __restrict__ out)
{
    __shared__ __align__(16) u16 sGF[TM * LDP];   // gf -> av -> pol2|valh2
    __shared__ __align__(16) u16 sHX0[TM * LDP];  // hx_old -> val -> pol1|valh1
    __shared__ __align__(16) u16 sHX1[TM * LDP];  // hx_new
    __shared__ __align__(16) u16 sKEY[TM * LDP];  // key_ -> attn_weight
    __shared__ __align__(16) u16 sG[4 * LDP];
    __shared__ int sIDX[TM];

    const bool isf32 = detect_f32(img);
    const int tid  = threadIdx.x;
    const int lane = tid & 63;
    const int wv   = tid >> 6;
    const int l15  = lane & 15;
    const int quad = lane >> 4;
    const int q8   = quad * 8;
    const int ln8  = lane * 8;
    const int row0 = blockIdx.x * TM;

    // ---- phase 0: idx + G table ----
    if (tid < TM) sIDX[tid] = insn[row0 + tid];
    for (int j = tid; j < 1024; j += 512) {
        int e = j >> 8, n = j & 255;
        float acc = ldin(b_ta, n, isf32);
        #pragma unroll
        for (int k = 0; k < 25; ++k)
            acc += ldin(emb, e * 25 + k, isf32) * ldin(w_ta, n * 25 + k, isf32);
        sG[e * LDP + n] = f2b(sigm(acc));
    }
    __syncthreads();

    // ---- phase 0b: stage gated_fusion = img * G[idx], and hx_old ----
    for (int it = tid; it < TM * 32; it += 512) {
        int r = it >> 5, c0 = (it & 31) << 3;
        int e = sIDX[r];
        u16x8 gv = *(const u16x8*)(sG + e * LDP + c0);
        float iv[8], hv[8];
        const size_t base = (size_t)(row0 + r) * 256 + c0;
        if (isf32) {
            const f32x4* ip = (const f32x4*)((const float*)img + base);
            const f32x4* hp = (const f32x4*)((const float*)hx_in + base);
            f32x4 a0 = __builtin_nontemporal_load(ip);
            f32x4 a1 = __builtin_nontemporal_load(ip + 1);
            f32x4 b0 = __builtin_nontemporal_load(hp);
            f32x4 b1 = __builtin_nontemporal_load(hp + 1);
            #pragma unroll
            for (int j = 0; j < 4; ++j) {
                iv[j] = a0[j]; iv[4 + j] = a1[j];
                hv[j] = b0[j]; hv[4 + j] = b1[j];
            }
        } else {
            u16x8 i8 = *(const u16x8*)((const u16*)img + base);
            u16x8 h8 = *(const u16x8*)((const u16*)hx_in + base);
            #pragma unroll
            for (int j = 0; j < 8; ++j) { iv[j] = b2f(i8[j]); hv[j] = b2f(h8[j]); }
        }
        u16x8 ov, hvv;
        #pragma unroll
        for (int j = 0; j < 8; ++j) {
            ov[j] = f2b(iv[j] * b2f(gv[j]));
            hvv[j] = f2b(hv[j]);
        }
        *(u16x8*)(sGF + r * LDP + c0) = ov;
        *(u16x8*)(sHX0 + r * LDP + c0) = hvv;
    }
    __syncthreads();

    // ---- t1: LSTM gates, B-stationary: wave owns col-tile c, loops m ----
    // c = wv*2 + pass: each wave covers 32 adjacent cols over its 2 passes, so
    // the two 64-B halves of every 128-B output line come from the SAME wave
    // (pass0/pass1) -> L2 merges the cn writeback, cx-in line hits on pass1.
    {
        int eIdx[2];
        #pragma unroll
        for (int m = 0; m < 2; ++m) eIdx[m] = sIDX[m * 16 + l15];
        const u16* bih0 = wsb + OFF_WIH + ln8;
        const u16* bhh0 = wsb + OFF_WHH + ln8;
        #pragma unroll 1
        for (int pass = 0; pass < 2; ++pass) {
            const int c = wv * 2 + pass;          // 0..15
            const int nc = c * 16 + l15;
            // prefetch cx-in (plain loads: keep line resident for sibling pass)
            float cxp[2][4];
            #pragma unroll
            for (int m = 0; m < 2; ++m)
                #pragma unroll
                for (int r = 0; r < 4; ++r)
                    cxp[m][r] = ldin(cx_in, (size_t)(row0 + m * 16 + quad * 4 + r) * 256 + nc, isf32);
            f32x4 acc[4][2] = {};                 // [gate][m]
            #pragma unroll
            for (int kk = 0; kk < 8; ++kk) {      // gf section (ih cols 0..255)
                bf16x8 a[2], b[4];
                #pragma unroll
                for (int m = 0; m < 2; ++m) a[m] = ld8(sGF + (m * 16 + l15) * LDP + kk * 32 + q8);
                #pragma unroll
                for (int g = 0; g < 4; ++g) b[g] = ld8(bih0 + (size_t)((g * 16 + c) * 16 + kk) * 512);
                #pragma unroll
                for (int g = 0; g < 4; ++g)
                    #pragma unroll
                    for (int m = 0; m < 2; ++m) acc[g][m] = mfma16(a[m], b[g], acc[g][m]);
            }
            #pragma unroll
            for (int kk = 0; kk < 8; ++kk) {      // ga section (ih cols 256..511)
                bf16x8 a[2], b[4];
                #pragma unroll
                for (int m = 0; m < 2; ++m) a[m] = ld8(sG + eIdx[m] * LDP + kk * 32 + q8);
                #pragma unroll
                for (int g = 0; g < 4; ++g) b[g] = ld8(bih0 + (size_t)((g * 16 + c) * 16 + 8 + kk) * 512);
                #pragma unroll
                for (int g = 0; g < 4; ++g)
                    #pragma unroll
                    for (int m = 0; m < 2; ++m) acc[g][m] = mfma16(a[m], b[g], acc[g][m]);
            }
            #pragma unroll
            for (int kk = 0; kk < 8; ++kk) {      // hx section (w_hh)
                bf16x8 a[2], b[4];
                #pragma unroll
                for (int m = 0; m < 2; ++m) a[m] = ld8(sHX0 + (m * 16 + l15) * LDP + kk * 32 + q8);
                #pragma unroll
                for (int g = 0; g < 4; ++g) b[g] = ld8(bhh0 + (size_t)((g * 16 + c) * 8 + kk) * 512);
                #pragma unroll
                for (int g = 0; g < 4; ++g)
                    #pragma unroll
                    for (int m = 0; m < 2; ++m) acc[g][m] = mfma16(a[m], b[g], acc[g][m]);
            }
            const float bi  = ldin(b_ih, nc, isf32)       + ldin(b_hh, nc, isf32);
            const float bff = ldin(b_ih, 256 + nc, isf32) + ldin(b_hh, 256 + nc, isf32);
            const float bg  = ldin(b_ih, 512 + nc, isf32) + ldin(b_hh, 512 + nc, isf32);
            const float bo  = ldin(b_ih, 768 + nc, isf32) + ldin(b_hh, 768 + nc, isf32);
            #pragma unroll
            for (int m = 0; m < 2; ++m) {
                #pragma unroll
                for (int r = 0; r < 4; ++r) {
                    const int grow = m * 16 + quad * 4 + r;
                    const size_t gidx = (size_t)(row0 + grow) * 256 + nc;
                    const float iv = sigm(acc[0][m][r] + bi);
                    const float fv = sigm(acc[1][m][r] + bff);
                    const float gv = tanhfast(acc[2][m][r] + bg);
                    const float ov = sigm(acc[3][m][r] + bo);
                    const float cn = fv * cxp[m][r] + iv * gv;
                    const float hn = ov * tanhfast(cn);
                    // cn: plain store so L2 merges the two half-line writes
                    stout(out, (size_t)(4 * BTOT) + (size_t)256 * BTOT + gidx, cn, isf32);
                    // hn: NOT stored here; streamed coalesced from sHX1 at t2.
                    sHX1[grow * LDP + nc] = f2b(hn);
                }
            }
        }
    }
    __syncthreads();

    // ---- t2: mlp_attn = relu([gf|hx_new] @ w_ba^T + b) -> key_ | val ----
    {
        // coalesced hx output stream from sHX1 (full 128-B lines, nt).
        // No barrier needed: t2 never writes sHX1.
        for (int it = tid; it < TM * 32; it += 512) {
            int r = it >> 5, c0 = (it & 31) << 3;
            u16x8 h8 = *(const u16x8*)(sHX1 + r * LDP + c0);
            const size_t base = (size_t)(4 * BTOT) + (size_t)(row0 + r) * 256 + c0;
            if (isf32) {
                f32x4 lo, hi;
                #pragma unroll
                for (int j = 0; j < 4; ++j) { lo[j] = b2f(h8[j]); hi[j] = b2f(h8[4 + j]); }
                __builtin_nontemporal_store(lo, (f32x4*)((float*)out + base));
                __builtin_nontemporal_store(hi, (f32x4*)((float*)out + base) + 1);
            } else {
                *(u16x8*)((u16*)out + base) = h8;
            }
        }
        f32x4 acc[4][2] = {};                     // [t][m], tiles wv*4+t (0..31)
        const u16* bb0 = wsb + OFF_WBA + ln8;
        #pragma unroll
        for (int kk = 0; kk < 8; ++kk) {          // gf
            bf16x8 a[2], b[4];
            #pragma unroll
            for (int m = 0; m < 2; ++m) a[m] = ld8(sGF + (m * 16 + l15) * LDP + kk * 32 + q8);
            #pragma unroll
            for (int t = 0; t < 4; ++t) b[t] = ld8(bb0 + (size_t)((wv * 4 + t) * 16 + kk) * 512);
            #pragma unroll
            for (int t = 0; t < 4; ++t)
                #pragma unroll
                for (int m = 0; m < 2; ++m) acc[t][m] = mfma16(a[m], b[t], acc[t][m]);
        }
        #pragma unroll
        for (int kk = 0; kk < 8; ++kk) {          // hx_new
            bf16x8 a[2], b[4];
            #pragma unroll
            for (int m = 0; m < 2; ++m) a[m] = ld8(sHX1 + (m * 16 + l15) * LDP + kk * 32 + q8);
            #pragma unroll
            for (int t = 0; t < 4; ++t) b[t] = ld8(bb0 + (size_t)((wv * 4 + t) * 16 + 8 + kk) * 512);
            #pragma unroll
            for (int t = 0; t < 4; ++t)
                #pragma unroll
                for (int m = 0; m < 2; ++m) acc[t][m] = mfma16(a[m], b[t], acc[t][m]);
        }
        #pragma unroll
        for (int t = 0; t < 4; ++t) {
            const int col = (wv * 4 + t) * 16 + l15;
            const float bb = ldin(b_ba, col, isf32);
            u16* dst = (col < 256) ? (sKEY + col) : (sHX0 + (col - 256));
            #pragma unroll
            for (int m = 0; m < 2; ++m)
                #pragma unroll
                for (int r = 0; r < 4; ++r)
                    dst[(m * 16 + quad * 4 + r) * LDP] = f2b(relu(acc[t][m][r] + bb));
        }
    }
    __syncthreads();

    // ---- t3: w_q/w_k GEMMs + tanh + *val -> attention_vector (sGF) ----
    {
        f32x4 cq[2][2] = {}, ck[2][2] = {};       // tiles wv*2+t (0..15)
        const u16* bq0 = wsb + OFF_WQ + ln8;
        const u16* bk0 = wsb + OFF_WK + ln8;
        #pragma unroll
        for (int kk = 0; kk < 8; ++kk) {
            bf16x8 aq[2], ak[2], bqf[2], bkf[2];
            #pragma unroll
            for (int m = 0; m < 2; ++m) {
                aq[m] = ldg8f_nt(query, (size_t)(row0 + m * 16 + l15) * 256 + kk * 32 + q8, isf32);
                ak[m] = ld8(sKEY + (m * 16 + l15) * LDP + kk * 32 + q8);
            }
            #pragma unroll
            for (int t = 0; t < 2; ++t) {
                bqf[t] = ld8(bq0 + (size_t)((wv * 2 + t) * 8 + kk) * 512);
                bkf[t] = ld8(bk0 + (size_t)((wv * 2 + t) * 8 + kk) * 512);
            }
            #pragma unroll
            for (int t = 0; t < 2; ++t)
                #pragma unroll
                for (int m = 0; m < 2; ++m) {
                    cq[t][m] = mfma16(aq[m], bqf[t], cq[t][m]);
                    ck[t][m] = mfma16(ak[m], bkf[t], ck[t][m]);
                }
        }
        #pragma unroll
        for (int t = 0; t < 2; ++t) {
            const int col = (wv * 2 + t) * 16 + l15;
            const float bqv = ldin(b_q, col, isf32);
            const float bkv = ldin(b_k, col, isf32);
            #pragma unroll
            for (int m = 0; m < 2; ++m)
                #pragma unroll
                for (int r = 0; r < 4; ++r) {
                    const int grow = m * 16 + quad * 4 + r;
                    const float u = tanhfast(relu(cq[t][m][r] + bqv) + relu(ck[t][m][r] + bkv));
                    sGF[grow * LDP + col] = f2b(u * b2f(sHX0[grow * LDP + col]));
                }
        }
    }
    __syncthreads();

    // ---- t4: attn_weight = relu([av|hx_new] @ w_at^T + b) -> sKEY ----
    {
        f32x4 acc[2][2] = {};                     // tiles wv*2+t (0..15)
        const u16* bb0 = wsb + OFF_WAT + ln8;
        #pragma unroll
        for (int kk = 0; kk < 8; ++kk) {          // av
            bf16x8 a[2], b[2];
            #pragma unroll
            for (int m = 0; m < 2; ++m) a[m] = ld8(sGF + (m * 16 + l15) * LDP + kk * 32 + q8);
            #pragma unroll
            for (int t = 0; t < 2; ++t) b[t] = ld8(bb0 + (size_t)((wv * 2 + t) * 16 + kk) * 512);
            #pragma unroll
            for (int t = 0; t < 2; ++t)
                #pragma unroll
                for (int m = 0; m < 2; ++m) acc[t][m] = mfma16(a[m], b[t], acc[t][m]);
        }
        #pragma unroll
        for (int kk = 0; kk < 8; ++kk) {          // hx_new
            bf16x8 a[2], b[2];
            #pragma unroll
            for (int m = 0; m < 2; ++m) a[m] = ld8(sHX1 + (m * 16 + l15) * LDP + kk * 32 + q8);
            #pragma unroll
            for (int t = 0; t < 2; ++t) b[t] = ld8(bb0 + (size_t)((wv * 2 + t) * 16 + 8 + kk) * 512);
            #pragma unroll
            for (int t = 0; t < 2; ++t)
                #pragma unroll
                for (int m = 0; m < 2; ++m) acc[t][m] = mfma16(a[m], b[t], acc[t][m]);
        }
        #pragma unroll
        for (int t = 0; t < 2; ++t) {
            const int col = (wv * 2 + t) * 16 + l15;
            const float bb = ldin(b_at, col, isf32);
            #pragma unroll
            for (int m = 0; m < 2; ++m)
                #pragma unroll
                for (int r = 0; r < 4; ++r)
                    sKEY[(m * 16 + quad * 4 + r) * LDP + col] = f2b(relu(acc[t][m][r] + bb));
        }
    }
    __syncthreads();

    // ---- t5: pol1 / valh1 -> sHX0 ----
    {
        const int m = wv & 1, half = wv >> 1;     // half 0..3
        const int arow = m * 16 + l15;
        bf16x8 afr[8];
        #pragma unroll
        for (int kk = 0; kk < 8; ++kk) afr[kk] = ld8(sKEY + arow * LDP + kk * 32 + q8);
        {   // pol1: N=128 (8 tiles), KK=8: tiles half*2+t
            f32x4 acc[2] = {};
            #pragma unroll
            for (int kk = 0; kk < 8; ++kk)
                #pragma unroll
                for (int t = 0; t < 2; ++t)
                    acc[t] = mfma16(afr[kk], ld8(wsb + OFF_WP1 + (size_t)((half * 2 + t) * 8 + kk) * 512 + ln8), acc[t]);
            #pragma unroll
            for (int t = 0; t < 2; ++t) {
                const int col = (half * 2 + t) * 16 + l15;
                const float bb = ldin(b_p1, col, isf32);
                #pragma unroll
                for (int r = 0; r < 4; ++r)
                    sHX0[(m * 16 + quad * 4 + r) * LDP + col] = f2b(relu(acc[t][r] + bb));
            }
        }
        {   // valh1: N=64 (4 tiles) -> sHX0 cols 128..191; tile = half
            f32x4 acc = {};
            #pragma unroll
            for (int kk = 0; kk < 8; ++kk)
                acc = mfma16(afr[kk], ld8(wsb + OFF_WV1 + (size_t)(half * 8 + kk) * 512 + ln8), acc);
            const int col = half * 16 + l15;
            const float bb = ldin(b_v1, col, isf32);
            #pragma unroll
            for (int r = 0; r < 4; ++r)
                sHX0[(m * 16 + quad * 4 + r) * LDP + 128 + col] = f2b(relu(acc[r] + bb));
        }
    }
    __syncthreads();

    // ---- t6: pol2 (K=128,N=64), valh2 (K=64,N=32) -> sGF ----
    {
        const int m = wv & 1, half = wv >> 1;     // half 0..3
        const int arow = m * 16 + l15;
        const u16* a0 = sHX0 + arow * LDP;
        bf16x8 ap[4], av2[2];
        #pragma unroll
        for (int kk = 0; kk < 4; ++kk) ap[kk] = ld8(a0 + kk * 32 + q8);
        #pragma unroll
        for (int kk = 0; kk < 2; ++kk) av2[kk] = ld8(a0 + 128 + kk * 32 + q8);
        {   // pol2: KK=4, 4 tiles: tile = half
            f32x4 acc = {};
            #pragma unroll
            for (int kk = 0; kk < 4; ++kk)
                acc = mfma16(ap[kk], ld8(wsb + OFF_WP2 + (size_t)(half * 4 + kk) * 512 + ln8), acc);
            const int col = half * 16 + l15;
            const float bb = ldin(b_p2, col, isf32);
            #pragma unroll
            for (int r = 0; r < 4; ++r)
                sGF[(m * 16 + quad * 4 + r) * LDP + col] = f2b(relu(acc[r] + bb));
        }
        if (half < 2) {   // valh2: KK=2, 2 tiles: tile = half -> sGF cols 64..95
            f32x4 acc = {};
            #pragma unroll
            for (int kk = 0; kk < 2; ++kk)
                acc = mfma16(av2[kk], ld8(wsb + OFF_WV2 + (size_t)(half * 2 + kk) * 512 + ln8), acc);
            const int col = half * 16 + l15;
            const float bb = ldin(b_v2, col, isf32);
            #pragma unroll
            for (int r = 0; r < 4; ++r)
                sGF[(m * 16 + quad * 4 + r) * LDP + 64 + col] = f2b(relu(acc[r] + bb));
        }
    }
    __syncthreads();

    // ---- t7: tiny heads ----
    if (tid < TM * 4) {
        const int r = tid >> 2, o = tid & 3;
        const int grow = row0 + r;
        const u16* rowp = sGF + r * LDP;
        if (o < 3) {
            float acc = ldin(b_p3, o, isf32);
            #pragma unroll
            for (int k = 0; k < 64; ++k) acc += b2f(rowp[k]) * ldin(w_p3, o * 64 + k, isf32);
            stout_nt(out, (size_t)BTOT + (size_t)grow * 3 + o, acc, isf32);
        } else {
            float acc = ldin(b_v3, 0, isf32);
            #pragma unroll
            for (int k = 0; k < 32; ++k) acc += b2f(rowp[64 + k]) * ldin(w_v3, k, isf32);
            stout_nt(out, (size_t)grow, acc, isf32);
        }
    }
}

extern "C" void kernel_launch(void* const* d_in, const int* in_sizes, int n_in,
                              void* d_out, int out_size, void* d_ws, size_t ws_size,
                              hipStream_t stream) {
    u16* ws = (u16*)d_ws;

    CvtArgs ca;
    const int srcIdx[10] = {8, 9, 12, 14, 16, 18, 20, 22, 26, 28};
    const unsigned int ns[10]   = {524288, 262144, 65536, 65536, 262144, 131072, 32768, 8192, 16384, 2048};
    const unsigned int off[10]  = {OFF_WIH, OFF_WHH, OFF_WQ, OFF_WK, OFF_WBA, OFF_WAT, OFF_WP1, OFF_WP2, OFF_WV1, OFF_WV2};
    const unsigned int kd[10]   = {512, 256, 256, 256, 512, 512, 256, 128, 256, 64};
    for (int i = 0; i < 10; ++i) {
        ca.src[i] = d_in[srcIdx[i]];
        ca.nchunk[i] = ns[i] / 8;
        ca.off8[i] = off[i] / 8;
        ca.Kdim[i] = kd[i];
    }
    ca.det = d_in[0];
    cvt_weights<<<dim3(10, 64), dim3(256), 0, stream>>>(ca, ws);

    ac_fused<<<dim3(BTOT / TM), dim3(512), 0, stream>>>(
        d_in[0], (const int*)d_in[1], d_in[2], d_in[3], d_in[4],
        d_in[5], d_in[6], d_in[7],
        d_in[10], d_in[11],           // b_ih, b_hh
        d_in[13], d_in[15],           // b_q, b_k
        d_in[17], d_in[19],           // b_ba, b_at
        d_in[21], d_in[23],           // b_p1, b_p2
        d_in[24], d_in[25],           // w_p, b_p
        d_in[27], d_in[29],           // b_v1, b_v2
        d_in[30], d_in[31],           // w_v, b_v
        (const u16*)d_ws, d_out);
}

// Round 4
// 418.415 us; speedup vs baseline: 1.5340x; 1.5340x over previous
//
#include <hip/hip_runtime.h>

typedef unsigned short u16;
typedef __bf16 bf16x8 __attribute__((ext_vector_type(8)));
typedef float f32x4 __attribute__((ext_vector_type(4)));
typedef u16 u16x8 __attribute__((ext_vector_type(8)));

#define TM 64
#define LDP 264          // padded LDS row stride (elems)
#define BTOT 32768

// bf16 frag-swizzled weight layout inside d_ws (element offsets)
#define OFF_WIH 0
#define OFF_WHH 524288
#define OFF_WQ  786432
#define OFF_WK  851968
#define OFF_WBA 917504
#define OFF_WAT 1179648
#define OFF_WP1 1310720
#define OFF_WP2 1343488
#define OFF_WV1 1351680
#define OFF_WV2 1368064

__device__ __forceinline__ float b2f(u16 h) {
    union { unsigned int u; float f; } v; v.u = ((unsigned int)h) << 16; return v.f;
}
__device__ __forceinline__ u16 f2b(float f) {
    union { float f; unsigned int u; } v; v.f = f;
    unsigned int u = v.u + 0x7fffu + ((v.u >> 16) & 1u);
    return (u16)(u >> 16);
}
__device__ __forceinline__ float sigm(float x) { return 1.0f / (1.0f + __expf(-x)); }
__device__ __forceinline__ float tanhfast(float x) { return 1.0f - 2.0f / (__expf(2.0f * x) + 1.0f); }
__device__ __forceinline__ float relu(float x) { return x > 0.0f ? x : 0.0f; }
__device__ __forceinline__ bf16x8 ld8(const u16* p) { return *(const bf16x8*)p; }
__device__ __forceinline__ f32x4 mfma16(bf16x8 a, bf16x8 b, f32x4 c) {
    return __builtin_amdgcn_mfma_f32_16x16x32_bf16(a, b, c, 0, 0, 0);
}

// dtype probe (data is f32): bf16-packed words carry an exponent field in
// bits 7..14; f32 words have mantissa bits there.
__device__ __forceinline__ bool detect_f32(const void* imgp) {
    const unsigned int* w = (const unsigned int*)imgp;
    int hits = 0;
    #pragma unroll
    for (int i = 0; i < 16; ++i) {
        int e0 = (w[i] >> 7) & 0xFF;
        hits += (e0 >= 100 && e0 <= 140) ? 1 : 0;
    }
    return hits < 10;
}

__device__ __forceinline__ float ldin(const void* p, size_t i, bool f32) {
    return f32 ? ((const float*)p)[i] : b2f(((const u16*)p)[i]);
}
__device__ __forceinline__ void stout(void* o, size_t i, float v, bool f32) {
    if (f32) ((float*)o)[i] = v; else ((u16*)o)[i] = f2b(v);
}
// non-temporal variants for streaming (read-once / write-once) traffic.
__device__ __forceinline__ float ldin_nt(const void* p, size_t i, bool f32) {
    return f32 ? __builtin_nontemporal_load((const float*)p + i)
               : b2f(((const u16*)p)[i]);
}
__device__ __forceinline__ void stout_nt(void* o, size_t i, float v, bool f32) {
    if (f32) __builtin_nontemporal_store(v, (float*)o + i);
    else ((u16*)o)[i] = f2b(v);
}
__device__ __forceinline__ bf16x8 ldg8f_nt(const void* p, size_t i, bool f32) {
    u16 t[8];
    if (f32) {
        const f32x4* q = (const f32x4*)((const float*)p + i);
        f32x4 a = __builtin_nontemporal_load(q);
        f32x4 b = __builtin_nontemporal_load(q + 1);
        #pragma unroll
        for (int j = 0; j < 4; ++j) { t[j] = f2b(a[j]); t[4 + j] = f2b(b[j]); }
    } else {
        *(u16x8*)t = *(const u16x8*)((const u16*)p + i);
    }
    return *(bf16x8*)t;
}

// ---- weight pre-conversion + MFMA-frag swizzle ----
// dst chunk g (8 elems): lane = g&63, fi = g>>6, kk = fi%KK, tn = fi/KK
// src: row = tn*16 + (lane&15), col = kk*32 + (lane>>4)*8  of W[N,K] row-major
struct CvtArgs {
    const void* src[10];
    unsigned int nchunk[10];
    unsigned int off8[10];
    unsigned int Kdim[10];
    const void* det;
};

__global__ __launch_bounds__(256) void cvt_weights(CvtArgs a, u16* ws) {
    const bool f32 = detect_f32(a.det);
    const int p = blockIdx.x;
    const void* s = a.src[p];
    const unsigned int K = a.Kdim[p];
    const unsigned int KK = K >> 5;          // pow2 for all matrices
    const unsigned int msk = KK - 1u;
    const unsigned int sh = 31 - __clz((int)KK);
    const unsigned int n = a.nchunk[p];
    for (unsigned int g = blockIdx.y * blockDim.x + threadIdx.x; g < n;
         g += gridDim.y * blockDim.x) {
        const unsigned int lane = g & 63u;
        const unsigned int fi = g >> 6;
        const unsigned int kk = fi & msk;
        const unsigned int tn = fi >> sh;
        const unsigned int row = tn * 16u + (lane & 15u);
        const unsigned int col = kk * 32u + ((lane >> 4) << 3);
        const size_t si = (size_t)row * K + col;
        u16 t[8];
        if (f32) {
            const float* q = (const float*)s + si;
            #pragma unroll
            for (int j = 0; j < 8; ++j) t[j] = f2b(__builtin_nontemporal_load(q + j));
        } else {
            *(u16x8*)t = *(const u16x8*)((const u16*)s + si);
        }
        ((u16x8*)ws)[a.off8[p] + g] = *(u16x8*)t;
    }
}

// TM=64 with 16 waves: LDS ~137 KB -> 1 block/CU = 4 waves/SIMD (same
// occupancy as TM=32 x 2 blocks), but HALF the total weight traffic:
// each weight fragment feeds 4 M-tiles (64 rows) instead of 2.
// launch_bounds(1024,2): occupancy is LDS-bound at 1 block anyway; give the
// register allocator up to 256 VGPRs for deeper load pipelining.
__global__ __launch_bounds__(1024, 2) void ac_fused(
    const void* __restrict__ img, const int* __restrict__ insn,
    const void* __restrict__ hx_in, const void* __restrict__ cx_in,
    const void* __restrict__ query,
    const void* __restrict__ emb, const void* __restrict__ w_ta, const void* __restrict__ b_ta,
    const void* __restrict__ b_ih, const void* __restrict__ b_hh,
    const void* __restrict__ b_q, const void* __restrict__ b_k,
    const void* __restrict__ b_ba, const void* __restrict__ b_at,
    const void* __restrict__ b_p1, const void* __restrict__ b_p2,
    const void* __restrict__ w_p3, const void* __restrict__ b_p3,
    const void* __restrict__ b_v1, const void* __restrict__ b_v2,
    const void* __restrict__ w_v3, const void* __restrict__ b_v3,
    const u16* __restrict__ wsb, void* __restrict__ out)
{
    __shared__ __align__(16) u16 sGF[TM * LDP];   // gf -> av -> pol2|valh2
    __shared__ __align__(16) u16 sHX0[TM * LDP];  // hx_old -> val -> pol1|valh1
    __shared__ __align__(16) u16 sHX1[TM * LDP];  // hx_new
    __shared__ __align__(16) u16 sKEY[TM * LDP];  // key_ -> attn_weight
    __shared__ __align__(16) u16 sG[4 * LDP];
    __shared__ int sIDX[TM];

    const bool isf32 = detect_f32(img);
    const int tid  = threadIdx.x;
    const int lane = tid & 63;
    const int wv   = tid >> 6;                    // 0..15
    const int l15  = lane & 15;
    const int quad = lane >> 4;
    const int q8   = quad * 8;
    const int ln8  = lane * 8;
    const int row0 = blockIdx.x * TM;

    // ---- phase 0: idx + G table (1024 threads: one elem each) ----
    if (tid < TM) sIDX[tid] = insn[row0 + tid];
    {
        int e = tid >> 8, n = tid & 255;
        float acc = ldin(b_ta, n, isf32);
        #pragma unroll
        for (int k = 0; k < 25; ++k)
            acc += ldin(emb, e * 25 + k, isf32) * ldin(w_ta, n * 25 + k, isf32);
        sG[e * LDP + n] = f2b(sigm(acc));
    }
    __syncthreads();

    // ---- phase 0b: stage gated_fusion = img * G[idx], and hx_old ----
    for (int it = tid; it < TM * 32; it += 1024) {
        int r = it >> 5, c0 = (it & 31) << 3;
        int e = sIDX[r];
        u16x8 gv = *(const u16x8*)(sG + e * LDP + c0);
        float iv[8], hv[8];
        const size_t base = (size_t)(row0 + r) * 256 + c0;
        if (isf32) {
            const f32x4* ip = (const f32x4*)((const float*)img + base);
            const f32x4* hp = (const f32x4*)((const float*)hx_in + base);
            f32x4 a0 = __builtin_nontemporal_load(ip);
            f32x4 a1 = __builtin_nontemporal_load(ip + 1);
            f32x4 b0 = __builtin_nontemporal_load(hp);
            f32x4 b1 = __builtin_nontemporal_load(hp + 1);
            #pragma unroll
            for (int j = 0; j < 4; ++j) {
                iv[j] = a0[j]; iv[4 + j] = a1[j];
                hv[j] = b0[j]; hv[4 + j] = b1[j];
            }
        } else {
            u16x8 i8 = *(const u16x8*)((const u16*)img + base);
            u16x8 h8 = *(const u16x8*)((const u16*)hx_in + base);
            #pragma unroll
            for (int j = 0; j < 8; ++j) { iv[j] = b2f(i8[j]); hv[j] = b2f(h8[j]); }
        }
        u16x8 ov, hvv;
        #pragma unroll
        for (int j = 0; j < 8; ++j) {
            ov[j] = f2b(iv[j] * b2f(gv[j]));
            hvv[j] = f2b(hv[j]);
        }
        *(u16x8*)(sGF + r * LDP + c0) = ov;
        *(u16x8*)(sHX0 + r * LDP + c0) = hvv;
    }
    __syncthreads();

    // ---- t1: LSTM gates. wave wv owns col-tile c=wv; 4 M-tiles share each
    // b-frag (2x the reuse of TM=32) ----
    {
        int eIdx[4];
        #pragma unroll
        for (int m = 0; m < 4; ++m) eIdx[m] = sIDX[m * 16 + l15];
        const u16* bih0 = wsb + OFF_WIH + ln8;
        const u16* bhh0 = wsb + OFF_WHH + ln8;
        const int c = wv;                         // 0..15, single pass
        f32x4 acc[4][4] = {};                     // [gate][m]
        #pragma unroll
        for (int kk = 0; kk < 8; ++kk) {          // gf section (ih cols 0..255)
            bf16x8 a[4], b[4];
            #pragma unroll
            for (int m = 0; m < 4; ++m) a[m] = ld8(sGF + (m * 16 + l15) * LDP + kk * 32 + q8);
            #pragma unroll
            for (int g = 0; g < 4; ++g) b[g] = ld8(bih0 + (size_t)((g * 16 + c) * 16 + kk) * 512);
            #pragma unroll
            for (int g = 0; g < 4; ++g)
                #pragma unroll
                for (int m = 0; m < 4; ++m) acc[g][m] = mfma16(a[m], b[g], acc[g][m]);
        }
        #pragma unroll
        for (int kk = 0; kk < 8; ++kk) {          // ga section (ih cols 256..511)
            bf16x8 a[4], b[4];
            #pragma unroll
            for (int m = 0; m < 4; ++m) a[m] = ld8(sG + eIdx[m] * LDP + kk * 32 + q8);
            #pragma unroll
            for (int g = 0; g < 4; ++g) b[g] = ld8(bih0 + (size_t)((g * 16 + c) * 16 + 8 + kk) * 512);
            #pragma unroll
            for (int g = 0; g < 4; ++g)
                #pragma unroll
                for (int m = 0; m < 4; ++m) acc[g][m] = mfma16(a[m], b[g], acc[g][m]);
        }
        #pragma unroll
        for (int kk = 0; kk < 8; ++kk) {          // hx section (w_hh)
            bf16x8 a[4], b[4];
            #pragma unroll
            for (int m = 0; m < 4; ++m) a[m] = ld8(sHX0 + (m * 16 + l15) * LDP + kk * 32 + q8);
            #pragma unroll
            for (int g = 0; g < 4; ++g) b[g] = ld8(bhh0 + (size_t)((g * 16 + c) * 8 + kk) * 512);
            #pragma unroll
            for (int g = 0; g < 4; ++g)
                #pragma unroll
                for (int m = 0; m < 4; ++m) acc[g][m] = mfma16(a[m], b[g], acc[g][m]);
        }
        const int nc = c * 16 + l15;
        const float bi  = ldin(b_ih, nc, isf32)       + ldin(b_hh, nc, isf32);
        const float bff = ldin(b_ih, 256 + nc, isf32) + ldin(b_hh, 256 + nc, isf32);
        const float bg  = ldin(b_ih, 512 + nc, isf32) + ldin(b_hh, 512 + nc, isf32);
        const float bo  = ldin(b_ih, 768 + nc, isf32) + ldin(b_hh, 768 + nc, isf32);
        #pragma unroll
        for (int m = 0; m < 4; ++m) {
            #pragma unroll
            for (int r = 0; r < 4; ++r) {
                const int grow = m * 16 + quad * 4 + r;
                const size_t gidx = (size_t)(row0 + grow) * 256 + nc;
                const float cxo = ldin_nt(cx_in, gidx, isf32);
                const float iv = sigm(acc[0][m][r] + bi);
                const float fv = sigm(acc[1][m][r] + bff);
                const float gv = tanhfast(acc[2][m][r] + bg);
                const float ov = sigm(acc[3][m][r] + bo);
                const float cn = fv * cxo + iv * gv;
                const float hn = ov * tanhfast(cn);
                stout_nt(out, (size_t)(4 * BTOT) + gidx, hn, isf32);
                stout_nt(out, (size_t)(4 * BTOT) + (size_t)256 * BTOT + gidx, cn, isf32);
                sHX1[grow * LDP + nc] = f2b(hn);
            }
        }
    }
    __syncthreads();

    // ---- t2: mlp_attn = relu([gf|hx_new] @ w_ba^T + b) -> key_ | val ----
    {
        f32x4 acc[2][4] = {};                     // [t][m], tiles wv*2+t (0..31)
        const u16* bb0 = wsb + OFF_WBA + ln8;
        #pragma unroll
        for (int kk = 0; kk < 8; ++kk) {          // gf
            bf16x8 a[4], b[2];
            #pragma unroll
            for (int m = 0; m < 4; ++m) a[m] = ld8(sGF + (m * 16 + l15) * LDP + kk * 32 + q8);
            #pragma unroll
            for (int t = 0; t < 2; ++t) b[t] = ld8(bb0 + (size_t)((wv * 2 + t) * 16 + kk) * 512);
            #pragma unroll
            for (int t = 0; t < 2; ++t)
                #pragma unroll
                for (int m = 0; m < 4; ++m) acc[t][m] = mfma16(a[m], b[t], acc[t][m]);
        }
        #pragma unroll
        for (int kk = 0; kk < 8; ++kk) {          // hx_new
            bf16x8 a[4], b[2];
            #pragma unroll
            for (int m = 0; m < 4; ++m) a[m] = ld8(sHX1 + (m * 16 + l15) * LDP + kk * 32 + q8);
            #pragma unroll
            for (int t = 0; t < 2; ++t) b[t] = ld8(bb0 + (size_t)((wv * 2 + t) * 16 + 8 + kk) * 512);
            #pragma unroll
            for (int t = 0; t < 2; ++t)
                #pragma unroll
                for (int m = 0; m < 4; ++m) acc[t][m] = mfma16(a[m], b[t], acc[t][m]);
        }
        #pragma unroll
        for (int t = 0; t < 2; ++t) {
            const int col = (wv * 2 + t) * 16 + l15;
            const float bb = ldin(b_ba, col, isf32);
            u16* dst = (col < 256) ? (sKEY + col) : (sHX0 + (col - 256));
            #pragma unroll
            for (int m = 0; m < 4; ++m)
                #pragma unroll
                for (int r = 0; r < 4; ++r)
                    dst[(m * 16 + quad * 4 + r) * LDP] = f2b(relu(acc[t][m][r] + bb));
        }
    }
    __syncthreads();

    // ---- t3: w_q/w_k GEMMs + tanh + *val -> attention_vector (sGF) ----
    {
        f32x4 cq[4] = {}, ck[4] = {};             // tile = wv (0..15)
        const u16* bq0 = wsb + OFF_WQ + ln8;
        const u16* bk0 = wsb + OFF_WK + ln8;
        #pragma unroll
        for (int kk = 0; kk < 8; ++kk) {
            bf16x8 aq[4], ak[4], bqf, bkf;
            #pragma unroll
            for (int m = 0; m < 4; ++m) {
                aq[m] = ldg8f_nt(query, (size_t)(row0 + m * 16 + l15) * 256 + kk * 32 + q8, isf32);
                ak[m] = ld8(sKEY + (m * 16 + l15) * LDP + kk * 32 + q8);
            }
            bqf = ld8(bq0 + (size_t)(wv * 8 + kk) * 512);
            bkf = ld8(bk0 + (size_t)(wv * 8 + kk) * 512);
            #pragma unroll
            for (int m = 0; m < 4; ++m) {
                cq[m] = mfma16(aq[m], bqf, cq[m]);
                ck[m] = mfma16(ak[m], bkf, ck[m]);
            }
        }
        const int col = wv * 16 + l15;
        const float bqv = ldin(b_q, col, isf32);
        const float bkv = ldin(b_k, col, isf32);
        #pragma unroll
        for (int m = 0; m < 4; ++m)
            #pragma unroll
            for (int r = 0; r < 4; ++r) {
                const int grow = m * 16 + quad * 4 + r;
                const float u = tanhfast(relu(cq[m][r] + bqv) + relu(ck[m][r] + bkv));
                sGF[grow * LDP + col] = f2b(u * b2f(sHX0[grow * LDP + col]));
            }
    }
    __syncthreads();

    // ---- t4: attn_weight = relu([av|hx_new] @ w_at^T + b) -> sKEY ----
    {
        f32x4 acc[4] = {};                        // tile = wv (0..15)
        const u16* bb0 = wsb + OFF_WAT + ln8;
        #pragma unroll
        for (int kk = 0; kk < 8; ++kk) {          // av
            bf16x8 a[4], b;
            #pragma unroll
            for (int m = 0; m < 4; ++m) a[m] = ld8(sGF + (m * 16 + l15) * LDP + kk * 32 + q8);
            b = ld8(bb0 + (size_t)(wv * 16 + kk) * 512);
            #pragma unroll
            for (int m = 0; m < 4; ++m) acc[m] = mfma16(a[m], b, acc[m]);
        }
        #pragma unroll
        for (int kk = 0; kk < 8; ++kk) {          // hx_new
            bf16x8 a[4], b;
            #pragma unroll
            for (int m = 0; m < 4; ++m) a[m] = ld8(sHX1 + (m * 16 + l15) * LDP + kk * 32 + q8);
            b = ld8(bb0 + (size_t)(wv * 16 + 8 + kk) * 512);
            #pragma unroll
            for (int m = 0; m < 4; ++m) acc[m] = mfma16(a[m], b, acc[m]);
        }
        const int col = wv * 16 + l15;
        const float bb = ldin(b_at, col, isf32);
        #pragma unroll
        for (int m = 0; m < 4; ++m)
            #pragma unroll
            for (int r = 0; r < 4; ++r)
                sKEY[(m * 16 + quad * 4 + r) * LDP + col] = f2b(relu(acc[m][r] + bb));
    }
    __syncthreads();

    // ---- t5: pol1 / valh1 -> sHX0 ----
    {
        const int m = wv & 3, half = wv >> 2;     // m 0..3, half 0..3
        const int arow = m * 16 + l15;
        bf16x8 afr[8];
        #pragma unroll
        for (int kk = 0; kk < 8; ++kk) afr[kk] = ld8(sKEY + arow * LDP + kk * 32 + q8);
        {   // pol1: N=128 (8 tiles), KK=8: tiles half*2+t
            f32x4 acc[2] = {};
            #pragma unroll
            for (int kk = 0; kk < 8; ++kk)
                #pragma unroll
                for (int t = 0; t < 2; ++t)
                    acc[t] = mfma16(afr[kk], ld8(wsb + OFF_WP1 + (size_t)((half * 2 + t) * 8 + kk) * 512 + ln8), acc[t]);
            #pragma unroll
            for (int t = 0; t < 2; ++t) {
                const int col = (half * 2 + t) * 16 + l15;
                const float bb = ldin(b_p1, col, isf32);
                #pragma unroll
                for (int r = 0; r < 4; ++r)
                    sHX0[(m * 16 + quad * 4 + r) * LDP + col] = f2b(relu(acc[t][r] + bb));
            }
        }
        {   // valh1: N=64 (4 tiles) -> sHX0 cols 128..191; tile = half
            f32x4 acc = {};
            #pragma unroll
            for (int kk = 0; kk < 8; ++kk)
                acc = mfma16(afr[kk], ld8(wsb + OFF_WV1 + (size_t)(half * 8 + kk) * 512 + ln8), acc);
            const int col = half * 16 + l15;
            const float bb = ldin(b_v1, col, isf32);
            #pragma unroll
            for (int r = 0; r < 4; ++r)
                sHX0[(m * 16 + quad * 4 + r) * LDP + 128 + col] = f2b(relu(acc[r] + bb));
        }
    }
    __syncthreads();

    // ---- t6: pol2 (K=128,N=64), valh2 (K=64,N=32) -> sGF ----
    {
        const int m = wv & 3, half = wv >> 2;     // m 0..3, half 0..3
        const int arow = m * 16 + l15;
        const u16* a0 = sHX0 + arow * LDP;
        bf16x8 ap[4], av2[2];
        #pragma unroll
        for (int kk = 0; kk < 4; ++kk) ap[kk] = ld8(a0 + kk * 32 + q8);
        #pragma unroll
        for (int kk = 0; kk < 2; ++kk) av2[kk] = ld8(a0 + 128 + kk * 32 + q8);
        {   // pol2: KK=4, 4 tiles: tile = half
            f32x4 acc = {};
            #pragma unroll
            for (int kk = 0; kk < 4; ++kk)
                acc = mfma16(ap[kk], ld8(wsb + OFF_WP2 + (size_t)(half * 4 + kk) * 512 + ln8), acc);
            const int col = half * 16 + l15;
            const float bb = ldin(b_p2, col, isf32);
            #pragma unroll
            for (int r = 0; r < 4; ++r)
                sGF[(m * 16 + quad * 4 + r) * LDP + col] = f2b(relu(acc[r] + bb));
        }
        if (half < 2) {   // valh2: KK=2, 2 tiles: tile = half -> sGF cols 64..95
            f32x4 acc = {};
            #pragma unroll
            for (int kk = 0; kk < 2; ++kk)
                acc = mfma16(av2[kk], ld8(wsb + OFF_WV2 + (size_t)(half * 2 + kk) * 512 + ln8), acc);
            const int col = half * 16 + l15;
            const float bb = ldin(b_v2, col, isf32);
            #pragma unroll
            for (int r = 0; r < 4; ++r)
                sGF[(m * 16 + quad * 4 + r) * LDP + 64 + col] = f2b(relu(acc[r] + bb));
        }
    }
    __syncthreads();

    // ---- t7: tiny heads ----
    if (tid < TM * 4) {
        const int r = tid >> 2, o = tid & 3;
        const int grow = row0 + r;
        const u16* rowp = sGF + r * LDP;
        if (o < 3) {
            float acc = ldin(b_p3, o, isf32);
            #pragma unroll
            for (int k = 0; k < 64; ++k) acc += b2f(rowp[k]) * ldin(w_p3, o * 64 + k, isf32);
            stout_nt(out, (size_t)BTOT + (size_t)grow * 3 + o, acc, isf32);
        } else {
            float acc = ldin(b_v3, 0, isf32);
            #pragma unroll
            for (int k = 0; k < 32; ++k) acc += b2f(rowp[64 + k]) * ldin(w_v3, k, isf32);
            stout_nt(out, (size_t)grow, acc, isf32);
        }
    }
}

extern "C" void kernel_launch(void* const* d_in, const int* in_sizes, int n_in,
                              void* d_out, int out_size, void* d_ws, size_t ws_size,
                              hipStream_t stream) {
    u16* ws = (u16*)d_ws;

    CvtArgs ca;
    const int srcIdx[10] = {8, 9, 12, 14, 16, 18, 20, 22, 26, 28};
    const unsigned int ns[10]   = {524288, 262144, 65536, 65536, 262144, 131072, 32768, 8192, 16384, 2048};
    const unsigned int off[10]  = {OFF_WIH, OFF_WHH, OFF_WQ, OFF_WK, OFF_WBA, OFF_WAT, OFF_WP1, OFF_WP2, OFF_WV1, OFF_WV2};
    const unsigned int kd[10]   = {512, 256, 256, 256, 512, 512, 256, 128, 256, 64};
    for (int i = 0; i < 10; ++i) {
        ca.src[i] = d_in[srcIdx[i]];
        ca.nchunk[i] = ns[i] / 8;
        ca.off8[i] = off[i] / 8;
        ca.Kdim[i] = kd[i];
    }
    ca.det = d_in[0];
    cvt_weights<<<dim3(10, 64), dim3(256), 0, stream>>>(ca, ws);

    ac_fused<<<dim3(BTOT / TM), dim3(1024), 0, stream>>>(
        d_in[0], (const int*)d_in[1], d_in[2], d_in[3], d_in[4],
        d_in[5], d_in[6], d_in[7],
        d_in[10], d_in[11],           // b_ih, b_hh
        d_in[13], d_in[15],           // b_q, b_k
        d_in[17], d_in[19],           // b_ba, b_at
        d_in[21], d_in[23],           // b_p1, b_p2
        d_in[24], d_in[25],           // w_p, b_p
        d_in[27], d_in[29],           // b_v1, b_v2
        d_in[30], d_in[31],           // w_v, b_v
        (const u16*)d_ws, d_out);
}